// Round 1
// baseline (85.868 us; speedup 1.0000x reference)
//
#include <hip/hip_runtime.h>
#include <math.h>

#define N_PTS 512
#define W_IMG 256
#define H_IMG 256
#define NPIX (W_IMG * H_IMG)

// ws SoA layout (floats): U,V,A,B,C,PR,PG,PB,AL,D,PT  -> 11 * 512
#define WS_U  0
#define WS_V  (1 * N_PTS)
#define WS_A  (2 * N_PTS)
#define WS_B  (3 * N_PTS)
#define WS_C  (4 * N_PTS)
#define WS_PR (5 * N_PTS)
#define WS_PG (6 * N_PTS)
#define WS_PB (7 * N_PTS)
#define WS_AL (8 * N_PTS)
#define WS_D  (9 * N_PTS)
#define WS_PT (10 * N_PTS)
#define WS_TOT (11 * N_PTS)

__global__ __launch_bounds__(N_PTS) void prep_kernel(
    const float* __restrict__ pc,      // N x 3
    const float* __restrict__ q,       // 1 x 4  (x,y,z,w)
    const float* __restrict__ t,       // 1 x 3
    const float* __restrict__ K,       // 3 x 3 row-major
    const float* __restrict__ color,   // N x 3
    const float* __restrict__ alpha,   // N
    const float* __restrict__ conic,   // N x 3 (a,b,c)
    float* __restrict__ ws)
{
    __shared__ float sd[N_PTS];
    __shared__ int   si[N_PTS];
    const int tid = threadIdx.x;

    const float qx = q[0], qy = q[1], qz = q[2], qw = q[3];
    const float R00 = 1.f - 2.f * (qy * qy + qz * qz);
    const float R01 = 2.f * (qx * qy - qz * qw);
    const float R02 = 2.f * (qx * qz + qy * qw);
    const float R10 = 2.f * (qx * qy + qz * qw);
    const float R11 = 1.f - 2.f * (qx * qx + qz * qz);
    const float R12 = 2.f * (qy * qz - qx * qw);
    const float R20 = 2.f * (qx * qz - qy * qw);
    const float R21 = 2.f * (qy * qz + qx * qw);
    const float R22 = 1.f - 2.f * (qx * qx + qy * qy);
    const float tx = t[0], ty = t[1], tz = t[2];

    // depth of my point
    {
        const float px = pc[tid * 3 + 0], py = pc[tid * 3 + 1], pz = pc[tid * 3 + 2];
        sd[tid] = R20 * px + R21 * py + R22 * pz + tz;
        si[tid] = tid;
    }
    __syncthreads();

    // bitonic sort ascending on (depth, idx)
    for (int k = 2; k <= N_PTS; k <<= 1) {
        for (int j = k >> 1; j > 0; j >>= 1) {
            const int i   = tid;
            const int ixj = i ^ j;
            if (ixj > i) {
                const float d1 = sd[i], d2 = sd[ixj];
                const int   i1 = si[i], i2 = si[ixj];
                const bool up = ((i & k) == 0);
                const bool gt = (d1 > d2) || (d1 == d2 && i1 > i2);
                if (gt == up) {
                    sd[i] = d2; sd[ixj] = d1;
                    si[i] = i2; si[ixj] = i1;
                }
            }
            __syncthreads();
        }
    }

    // gather sorted point data, recompute projection for my source point
    const int src = si[tid];
    const float px = pc[src * 3 + 0], py = pc[src * 3 + 1], pz = pc[src * 3 + 2];
    const float cxp = R00 * px + R01 * py + R02 * pz + tx;
    const float cyp = R10 * px + R11 * py + R12 * pz + ty;
    const float czp = R20 * px + R21 * py + R22 * pz + tz;
    const float fx = K[0], fy = K[4], cu = K[2], cv = K[5];

    const float al = alpha[src];

    ws[WS_U  + tid] = cxp * fx / czp + cu;
    ws[WS_V  + tid] = cyp * fy / czp + cv;
    ws[WS_A  + tid] = conic[src * 3 + 0];
    ws[WS_B  + tid] = conic[src * 3 + 1];
    ws[WS_C  + tid] = conic[src * 3 + 2];
    ws[WS_PR + tid] = color[src * 3 + 0];
    ws[WS_PG + tid] = color[src * 3 + 1];
    ws[WS_PB + tid] = color[src * 3 + 2];
    ws[WS_AL + tid] = al;
    ws[WS_D  + tid] = czp;
    // prune threshold: alpha==0 iff exp(pw)*al < 1/255 iff pw < -log(255*al).
    // subtract margin so float-rounding boundary cases still take the exact path.
    ws[WS_PT + tid] = -__logf(255.0f * al) - 0.01f;
}

__global__ __launch_bounds__(256) void raster_kernel(
    const float* __restrict__ ws,
    float* __restrict__ out)
{
    __shared__ float s[WS_TOT];
    const int tid = threadIdx.x;
    for (int i = tid; i < WS_TOT; i += 256) s[i] = ws[i];
    __syncthreads();

    const float* U  = s + WS_U;
    const float* V  = s + WS_V;
    const float* A  = s + WS_A;
    const float* B  = s + WS_B;
    const float* C  = s + WS_C;
    const float* PR = s + WS_PR;
    const float* PG = s + WS_PG;
    const float* PB = s + WS_PB;
    const float* AL = s + WS_AL;
    const float* D  = s + WS_D;
    const float* PT = s + WS_PT;

    const int pix = blockIdx.x * 256 + tid;
    const int wx = pix & (W_IMG - 1);
    const int hy = pix >> 8;
    const float up = (float)wx + 0.5f;
    const float vp = (float)hy + 0.5f;

    float T = 1.0f;
    float rr = 0.f, gg = 0.f, bb = 0.f, dd = 0.f, aa = 0.f;

    for (int n = 0; n < N_PTS; ++n) {
        const float dx = up - U[n];
        const float dy = vp - V[n];
        const float pw = -0.5f * (A[n] * dx * dx + C[n] * dy * dy) - B[n] * dx * dy;
        if (pw >= PT[n]) {
            const float g  = __expf(pw);
            const float pa = g * AL[n];
            if (pa >= (1.0f / 255.0f)) {
                const float al = fminf(pa, 0.99f);
                const float w  = al * T;
                rr = fmaf(w, PR[n], rr);
                gg = fmaf(w, PG[n], gg);
                bb = fmaf(w, PB[n], bb);
                dd = fmaf(w, D[n], dd);
                aa += w;
                T *= (1.0f - al);
            }
        }
        if (((n & 63) == 63) && __all(T < 1e-6f)) break;
    }

    const int base = pix * 3;
    out[base + 0] = rr;
    out[base + 1] = gg;
    out[base + 2] = bb;
    out[NPIX * 3 + pix] = dd;
    out[NPIX * 4 + pix] = aa;
}

extern "C" void kernel_launch(void* const* d_in, const int* in_sizes, int n_in,
                              void* d_out, int out_size, void* d_ws, size_t ws_size,
                              hipStream_t stream) {
    const float* pc    = (const float*)d_in[0];
    const float* q     = (const float*)d_in[1];
    const float* t     = (const float*)d_in[2];
    const float* K     = (const float*)d_in[3];
    const float* color = (const float*)d_in[4];
    const float* alpha = (const float*)d_in[5];
    const float* conic = (const float*)d_in[6];
    float* out = (float*)d_out;
    float* ws  = (float*)d_ws;

    prep_kernel<<<1, N_PTS, 0, stream>>>(pc, q, t, K, color, alpha, conic, ws);
    raster_kernel<<<NPIX / 256, 256, 0, stream>>>(ws, out);
}

// Round 2
// 31.773 us; speedup vs baseline: 2.7026x; 2.7026x over previous
//
#include <hip/hip_runtime.h>
#include <math.h>

#define N_PTS 512
#define W_IMG 256
#define H_IMG 256
#define NPIX (W_IMG * H_IMG)
#define NSEG 4
#define SEG_LEN (N_PTS / NSEG)

// ws layout: float4 PK0[512] | PK1[512] | PK2[512]
//   PK0 = (U, V, A, B)   PK1 = (C, PT, AL, D)   PK2 = (PR, PG, PB, 0)

__global__ __launch_bounds__(N_PTS) void prep_kernel(
    const float* __restrict__ pc,      // N x 3
    const float* __restrict__ q,       // 1 x 4  (x,y,z,w)
    const float* __restrict__ t,       // 1 x 3
    const float* __restrict__ K,       // 3 x 3 row-major
    const float* __restrict__ color,   // N x 3
    const float* __restrict__ alpha,   // N
    const float* __restrict__ conic,   // N x 3 (a,b,c)
    float4* __restrict__ ws4)
{
    __shared__ float sd[N_PTS];
    __shared__ int   si[N_PTS];
    const int tid = threadIdx.x;

    const float qx = q[0], qy = q[1], qz = q[2], qw = q[3];
    const float R00 = 1.f - 2.f * (qy * qy + qz * qz);
    const float R01 = 2.f * (qx * qy - qz * qw);
    const float R02 = 2.f * (qx * qz + qy * qw);
    const float R10 = 2.f * (qx * qy + qz * qw);
    const float R11 = 1.f - 2.f * (qx * qx + qz * qz);
    const float R12 = 2.f * (qy * qz - qx * qw);
    const float R20 = 2.f * (qx * qz - qy * qw);
    const float R21 = 2.f * (qy * qz + qx * qw);
    const float R22 = 1.f - 2.f * (qx * qx + qy * qy);
    const float tx = t[0], ty = t[1], tz = t[2];

    {
        const float px = pc[tid * 3 + 0], py = pc[tid * 3 + 1], pz = pc[tid * 3 + 2];
        sd[tid] = R20 * px + R21 * py + R22 * pz + tz;
        si[tid] = tid;
    }
    __syncthreads();

    // bitonic sort ascending on (depth, idx)
    for (int k = 2; k <= N_PTS; k <<= 1) {
        for (int j = k >> 1; j > 0; j >>= 1) {
            const int i   = tid;
            const int ixj = i ^ j;
            if (ixj > i) {
                const float d1 = sd[i], d2 = sd[ixj];
                const int   i1 = si[i], i2 = si[ixj];
                const bool up = ((i & k) == 0);
                const bool gt = (d1 > d2) || (d1 == d2 && i1 > i2);
                if (gt == up) {
                    sd[i] = d2; sd[ixj] = d1;
                    si[i] = i2; si[ixj] = i1;
                }
            }
            __syncthreads();
        }
    }

    const int src = si[tid];
    const float px = pc[src * 3 + 0], py = pc[src * 3 + 1], pz = pc[src * 3 + 2];
    const float cxp = R00 * px + R01 * py + R02 * pz + tx;
    const float cyp = R10 * px + R11 * py + R12 * pz + ty;
    const float czp = R20 * px + R21 * py + R22 * pz + tz;
    const float fx = K[0], fy = K[4], cu = K[2], cv = K[5];

    const float al = alpha[src];
    const float u  = cxp * fx / czp + cu;
    const float v  = cyp * fy / czp + cv;
    // prune threshold: contribution is zero iff exp(pw)*al < 1/255, i.e.
    // pw < -log(255*al). Margin 0.01 so float boundary cases take exact path.
    const float pt = -__logf(255.0f * al) - 0.01f;

    ws4[tid] = make_float4(u, v, conic[src * 3 + 0], conic[src * 3 + 1]);
    ws4[N_PTS + tid] = make_float4(conic[src * 3 + 2], pt, al, czp);
    ws4[2 * N_PTS + tid] = make_float4(color[src * 3 + 0], color[src * 3 + 1],
                                       color[src * 3 + 2], 0.f);
}

__global__ __launch_bounds__(256) void raster_kernel(
    const float4* __restrict__ ws4,
    float* __restrict__ out)
{
    const int tid  = threadIdx.x;
    const int lane = tid & 63;
    // force wave-uniform segment id into an SGPR so point loads scalarize
    const int seg  = __builtin_amdgcn_readfirstlane(tid >> 6);

    const int pix = blockIdx.x * 64 + lane;          // 64 consecutive px / row
    const float up = (float)(pix & (W_IMG - 1)) + 0.5f;
    const float vp = (float)(pix >> 8) + 0.5f;

    const float4* __restrict__ PK0 = ws4;
    const float4* __restrict__ PK1 = ws4 + N_PTS;
    const float4* __restrict__ PK2 = ws4 + 2 * N_PTS;

    float T = 1.f, rr = 0.f, gg = 0.f, bb = 0.f, dd = 0.f, aa = 0.f;

    const int n0 = seg * SEG_LEN;
    #pragma unroll 4
    for (int i = 0; i < SEG_LEN; ++i) {
        const int n = n0 + i;                        // wave-uniform -> s_load
        const float4 p0 = PK0[n];                    // U V A B
        const float4 p1 = PK1[n];                    // C PT AL D
        const float dx = up - p0.x;
        const float dy = vp - p0.y;
        const float pw = fmaf(-0.5f * p0.z, dx * dx,
                         fmaf(-0.5f * p1.x, dy * dy, -p0.w * (dx * dy)));
        if (__any(pw >= p1.y)) {
            const float pa = __expf(pw) * p1.z;
            // pw < PT implies pa < e^-0.01/255 < 1/255, so pa test is exact
            const float alEff = (pa >= (1.0f / 255.0f)) ? fminf(pa, 0.99f) : 0.f;
            const float w = alEff * T;
            const float4 p2 = PK2[n];                // PR PG PB
            rr = fmaf(w, p2.x, rr);
            gg = fmaf(w, p2.y, gg);
            bb = fmaf(w, p2.z, bb);
            dd = fmaf(w, p1.w, dd);
            aa += w;
            T = fmaf(-alEff, T, T);                  // T *= (1 - alEff)
        }
    }

    // ordered combine of the 4 depth segments: (c,T) = (c0 + T0*c1, T0*T1) ...
    __shared__ float part[NSEG][6][64];
    part[seg][0][lane] = rr;
    part[seg][1][lane] = gg;
    part[seg][2][lane] = bb;
    part[seg][3][lane] = dd;
    part[seg][4][lane] = aa;
    part[seg][5][lane] = T;
    __syncthreads();

    if (tid < 64) {
        float c0 = part[0][0][tid], c1 = part[0][1][tid], c2 = part[0][2][tid];
        float c3 = part[0][3][tid], c4 = part[0][4][tid];
        float Tacc = part[0][5][tid];
        #pragma unroll
        for (int s = 1; s < NSEG; ++s) {
            c0 = fmaf(Tacc, part[s][0][tid], c0);
            c1 = fmaf(Tacc, part[s][1][tid], c1);
            c2 = fmaf(Tacc, part[s][2][tid], c2);
            c3 = fmaf(Tacc, part[s][3][tid], c3);
            c4 = fmaf(Tacc, part[s][4][tid], c4);
            Tacc *= part[s][5][tid];
        }
        const int p = blockIdx.x * 64 + tid;
        out[p * 3 + 0] = c0;
        out[p * 3 + 1] = c1;
        out[p * 3 + 2] = c2;
        out[NPIX * 3 + p] = c3;
        out[NPIX * 4 + p] = c4;
    }
}

extern "C" void kernel_launch(void* const* d_in, const int* in_sizes, int n_in,
                              void* d_out, int out_size, void* d_ws, size_t ws_size,
                              hipStream_t stream) {
    const float* pc    = (const float*)d_in[0];
    const float* q     = (const float*)d_in[1];
    const float* t     = (const float*)d_in[2];
    const float* K     = (const float*)d_in[3];
    const float* color = (const float*)d_in[4];
    const float* alpha = (const float*)d_in[5];
    const float* conic = (const float*)d_in[6];
    float* out  = (float*)d_out;
    float4* ws4 = (float4*)d_ws;

    prep_kernel<<<1, N_PTS, 0, stream>>>(pc, q, t, K, color, alpha, conic, ws4);
    raster_kernel<<<NPIX / 64, 256, 0, stream>>>(ws4, out);
}